// Round 5
// baseline (171.396 us; speedup 1.0000x reference)
//
#include <hip/hip_runtime.h>
#include <hip/hip_bf16.h>

// LocalActivationUnit: score[b,t] = relu([q,k,q-k,q*k]·W0 + b0)·W1 + b1
// Folded: Wb[e][h] = W0b - W0c + q[e]*W0d ;  bias[h] = q·(W0a+W0c) + b0
//         h = relu(k·Wb + bias);  score = h·W1 + b1
// One block/batch; per-batch 200x128x64 bf16 MFMA GEMM.
//
// R4 -> R5: keys now staged to wave-private LDS via global_load_lds width=16
// (contiguous 1KB/instr, sequential DRAM streaming) instead of per-lane
// 16-row x 32B gathers (suspected ~3 TB/s effective). Global source is
// XOR-swizzled (unit ^= row&7) so the forced lane-contiguous LDS layout is
// bank-conflict-free for the MFMA A-frag ds_read_b128s. B-frags hoisted back
// to VGPRs (staging frees the load registers; LDS caps us at 3 blocks/CU so
// the VGPR budget at __launch_bounds__(256,3) is ~170).

#define TB 200
#define EB 128
#define HB 64

typedef __attribute__((ext_vector_type(8))) short bf16x8;
typedef __attribute__((ext_vector_type(4))) float f32x4;

typedef __attribute__((address_space(3))) void lds_vp;
typedef const __attribute__((address_space(1))) void gbl_vp;

__global__ __launch_bounds__(256, 3)
void lau_kernel(const float* __restrict__ query,
                const float* __restrict__ keys,
                const float* __restrict__ W0,
                const float* __restrict__ b0,
                const float* __restrict__ W1,
                const float* __restrict__ b1,
                float* __restrict__ out)
{
    const int b   = blockIdx.x;
    const int tid = threadIdx.x;

    __shared__ float q_s[EB];
    __shared__ float bias_s[HB];
    __shared__ float w1_s[HB];
    __shared__ float red_s[256];
    // WbT[h][e] bf16, row stride 136 elems (bank phase 16B-unit-uniform)
    __shared__ __align__(16) __hip_bfloat16 wbt[HB][EB + 8];
    // per-wave 16x128-f32 key tile, XOR-swizzled 16B units
    __shared__ __align__(16) float atile[4][2048];

    if (tid < EB) q_s[tid] = query[(size_t)b * EB + tid];
    __syncthreads();

    // ---- per-batch weight fold + bias partials ----
    {
        const int h     = tid & 63;
        const int chunk = tid >> 6;
        float biasp = 0.f;
        #pragma unroll 8
        for (int i = 0; i < 32; ++i) {
            const int e = chunk * 32 + i;
            const float qe  = q_s[e];
            const float w0a = W0[(size_t)e            * HB + h];
            const float w0b = W0[(size_t)(EB + e)     * HB + h];
            const float w0c = W0[(size_t)(2 * EB + e) * HB + h];
            const float w0d = W0[(size_t)(3 * EB + e) * HB + h];
            wbt[h][e] = __float2bfloat16(w0b - w0c + qe * w0d);
            biasp += qe * (w0a + w0c);
        }
        red_s[tid] = biasp;
    }
    __syncthreads();
    if (tid < HB) {
        bias_s[tid] = red_s[tid] + red_s[tid + 64] + red_s[tid + 128] + red_s[tid + 192] + b0[tid];
        w1_s[tid]   = W1[tid];
    }
    __syncthreads();

    const int lane = tid & 63;
    const int wave = tid >> 6;
    const int ln15 = lane & 15;
    const int quad = lane >> 4;
    const int m7   = ln15 & 7;

    // ---- hoist all B fragments into registers (16 x 4 VGPR) ----
    bf16x8 bfrag[4][4];
    #pragma unroll
    for (int nt = 0; nt < 4; ++nt)
        #pragma unroll
        for (int ks = 0; ks < 4; ++ks)
            bfrag[nt][ks] = *(const bf16x8*)&wbt[nt * 16 + ln15][ks * 32 + quad * 8];

    float w1q[4], biasq[4];
    #pragma unroll
    for (int nt = 0; nt < 4; ++nt) {
        w1q[nt]   = w1_s[nt * 16 + ln15];
        biasq[nt] = bias_s[nt * 16 + ln15];
    }

    const float* kb  = keys + (size_t)b * TB * EB;
    const float  b1v = b1[0];

    // staging lane constants: instr i covers tile rows 2i,2i+1; lane l -> row
    // 2i+(l>>5), 16B-unit (l&31)^(row&7); LDS dest is forced base + l*16.
    const int rlo  = lane >> 5;
    const int c16s = lane & 31;
    float* mytile = atile[wave];

    for (int mt = wave; mt < 13; mt += 4) {
        // ---- stage 16x128 tile (8KB) into wave-private LDS, swizzled ----
        #pragma unroll
        for (int i = 0; i < 8; ++i) {
            const int r  = 2 * i + rlo;
            int rg = mt * 16 + r;
            rg = rg < TB ? rg : TB - 1;                 // clamp masked tail rows
            const float* gp = kb + (size_t)rg * EB + ((c16s ^ (r & 7)) << 2);
            __builtin_amdgcn_global_load_lds((gbl_vp*)gp, (lds_vp*)(mytile + i * 256), 16, 0, 0);
        }
        __builtin_amdgcn_s_waitcnt(0);   // drain staging before LDS reads

        f32x4 acc[4] = {{0,0,0,0},{0,0,0,0},{0,0,0,0},{0,0,0,0}};
        #pragma unroll
        for (int ks = 0; ks < 4; ++ks) {
            // A-frag: floats [m][quad*8 + ks*32 .. +8) at swizzled units
            const int u0 = ((quad * 2 + ks * 8)     ^ m7) << 2;
            const int u1 = ((quad * 2 + ks * 8 + 1) ^ m7) << 2;
            const float4 a0 = *(const float4*)&mytile[ln15 * 128 + u0];
            const float4 a1 = *(const float4*)&mytile[ln15 * 128 + u1];
            union { bf16x8 v; __hip_bfloat162 h2[4]; } u;
            u.h2[0] = __float22bfloat162_rn(make_float2(a0.x, a0.y));
            u.h2[1] = __float22bfloat162_rn(make_float2(a0.z, a0.w));
            u.h2[2] = __float22bfloat162_rn(make_float2(a1.x, a1.y));
            u.h2[3] = __float22bfloat162_rn(make_float2(a1.z, a1.w));
            #pragma unroll
            for (int nt = 0; nt < 4; ++nt)
                acc[nt] = __builtin_amdgcn_mfma_f32_16x16x32_bf16(u.v, bfrag[nt][ks], acc[nt], 0, 0, 0);
        }

        // ---- epilogue: relu+bias, dot W1, reduce over n lanes ----
        float part[4];
        #pragma unroll
        for (int r = 0; r < 4; ++r) {
            float s = 0.f;
            #pragma unroll
            for (int nt = 0; nt < 4; ++nt) {
                float hv = acc[nt][r] + biasq[nt];
                hv = hv > 0.f ? hv : 0.f;
                s += hv * w1q[nt];
            }
            part[r] = s;
        }
        #pragma unroll
        for (int m = 1; m < 16; m <<= 1) {
            #pragma unroll
            for (int r = 0; r < 4; ++r)
                part[r] += __shfl_xor(part[r], m, 64);
        }
        if (ln15 == 0) {
            #pragma unroll
            for (int r = 0; r < 4; ++r) {
                const int mg = mt * 16 + quad * 4 + r;
                if (mg < TB) out[(size_t)b * TB + mg] = part[r] + b1v;
            }
        }
    }
}

extern "C" void kernel_launch(void* const* d_in, const int* in_sizes, int n_in,
                              void* d_out, int out_size, void* d_ws, size_t ws_size,
                              hipStream_t stream) {
    const float* query = (const float*)d_in[0];
    const float* keys  = (const float*)d_in[1];
    const float* W0    = (const float*)d_in[2];
    const float* b0    = (const float*)d_in[3];
    const float* W1    = (const float*)d_in[4];
    const float* b1    = (const float*)d_in[5];
    float* out = (float*)d_out;

    lau_kernel<<<1024, 256, 0, stream>>>(query, keys, W0, b0, W1, b1, out);
}